// Round 8
// baseline (346.452 us; speedup 1.0000x reference)
//
#include <hip/hip_runtime.h>
#include <hip/hip_bf16.h>

// Implicit-GEMM conv: M = 32*54*54 = 93312, N = 256 (co), K = 9*256 = 2304.
// R10: fully LDS-free GEMM. Both operands stream global->registers:
//   - cvt_xw emits x in k-major layout xb2[cq 32][n 32][h 56][w 56][e 8]
//     (pure permute of the bf16 cast). A-frag load for 16 consecutive m-rows
//     = contiguous 16x16B (consecutive m == consecutive ow), per-lane fq adds
//     a far 256B segment -> 4 segments/instr, same shape as R9's B loads.
//   - B path identical to R9 (Wt2 [kq 288][co 256][8], L2-hot).
//   - NO LDS, NO barriers, NO inline asm: 12 free-running waves/CU
//     (256 thr/block, launch_bounds(256,3)), register-double-buffered frags
//     (named F0/F1, x2 unroll), compiler-placed waitcnts.
//   - block-tile 128x128 (grid 1458 = 729 m x 2 co), wave-tile 64x64.
// R9 measured: taking B off the DS pipe = 141->119.5us, conflicts exactly
// halved; remaining wall was the per-tile barrier lockstep -> removed here.

typedef __bf16 bf16x8 __attribute__((ext_vector_type(8)));
typedef float f32x4 __attribute__((ext_vector_type(4)));

static __device__ __forceinline__ unsigned short f2bf(float f) {
    unsigned int u = __float_as_uint(f);
    unsigned int r = u + 0x7FFFu + ((u >> 16) & 1u);  // RNE
    return (unsigned short)(r >> 16);
}

// ---- conversion ----
// x-path (blocks [0,14336)): one wave per (cq, n, h); lane = w (0..55).
//   read  x[n][h][w][cq*8 .. +8]            (32B per lane, 1KB lane stride)
//   write xb2[cq][n][h][w][0..8]            (16B per lane, contiguous run)
// w-path (blocks [14336,14592)): Wt2[kq][co][8] as R9.
__global__ __launch_bounds__(256) void cvt_xw(
    const float* __restrict__ x, unsigned short* __restrict__ xb,
    const float* __restrict__ w, unsigned short* __restrict__ wt) {
    if (blockIdx.x < 14336) {
        const int wave = threadIdx.x >> 6, lane = threadIdx.x & 63;
        const int idx = blockIdx.x * 4 + wave;        // 0..57343
        const int cq  = idx / 1792;                   // 32*56
        const int rem = idx - cq * 1792;
        const int n   = rem / 56;
        const int h   = rem - n * 56;
        if (lane < 56) {
            const float* src = x + ((((n * 56 + h) * 56 + lane) << 8) + cq * 8);
            float4 a = *(const float4*)src;
            float4 b = *(const float4*)(src + 4);
            ushort4 o0 = {f2bf(a.x), f2bf(a.y), f2bf(a.z), f2bf(a.w)};
            ushort4 o1 = {f2bf(b.x), f2bf(b.y), f2bf(b.z), f2bf(b.w)};
            unsigned short* d = xb + ((((cq * 32 + n) * 56 + h) * 56 + lane) * 8);
            *(ushort4*)d = o0;
            *(ushort4*)(d + 4) = o1;
        }
    } else {
        int co = blockIdx.x - 14336;
        int ci = threadIdx.x;
        const float* src = w + co * 2304 + ci * 9;
        unsigned short* dst = wt + ((ci >> 3) * 256 + co) * 8 + (ci & 7);
#pragma unroll
        for (int khw = 0; khw < 9; ++khw) {
            float v = src[khw];
            v = (fabsf(v) < 0.01f) ? 0.0f : v;
            dst[khw * 65536] = f2bf(v);   // khw*32 chunks * 256 co * 8 elem
        }
    }
}

struct Frags { bf16x8 a[4]; bf16x8 b[4]; };

static __device__ __forceinline__ void mfma16(const Frags& f, f32x4 (&acc)[4][4]) {
    __builtin_amdgcn_s_setprio(1);
#pragma unroll
    for (int mi = 0; mi < 4; ++mi)
#pragma unroll
        for (int ni = 0; ni < 4; ++ni)
            acc[mi][ni] = __builtin_amdgcn_mfma_f32_16x16x32_bf16(
                f.a[mi], f.b[ni], acc[mi][ni], 0, 0, 0);
    __builtin_amdgcn_s_setprio(0);
}

// ---- GEMM: Out[m][co] = sum_k A[m][k]*W[co][k] + bias[co] ----
__global__ __launch_bounds__(256, 3) void conv_gemm(
    const unsigned short* __restrict__ Xb,   // xb2 [cq 32][n 32][h 56][w 56][8]
    const unsigned short* __restrict__ Wt,   // Wt2 [kq 288][co 256][8]
    const float* __restrict__ bias,          // [256]
    float* __restrict__ Out)                 // [93312][256]
{
    const int tid  = threadIdx.x;            // 0..255
    const int lane = tid & 63;
    const int wave = tid >> 6;               // 0..3

    const int bx  = blockIdx.x;              // 1458 = 729 m-tiles x 2 co-halves
    const int m0  = (bx >> 1) * 128;
    const int co0 = (bx & 1) * 128;

    const int fm = lane & 15;                // A-row / B-co within 16
    const int fq = lane >> 4;                // k-octet index within the 32-k tile
    const int wm = (wave >> 1) * 64;
    const int wn = (wave & 1) * 64;

    // per-mi A base pointers: elem off = ((fq*32 + n)*56 + oh)*448 + ow*8
    const unsigned short* a_ptr[4];
#pragma unroll
    for (int mi = 0; mi < 4; ++mi) {
        int m = m0 + wm + mi * 16 + fm;
        int n = m / 2916;
        int rem = m - n * 2916;
        int oh = rem / 54;
        int ow = rem - oh * 54;
        a_ptr[mi] = Xb + (((fq * 32 + n) * 56 + oh) * 56 + ow) * 8;
    }
    // B base: elem off = (t*4+fq)*2048 + co*8
    const unsigned short* b_ptr = Wt + (fq * 256 + co0 + wn + fm) * 8;

    f32x4 acc[4][4];
#pragma unroll
    for (int i = 0; i < 4; ++i)
#pragma unroll
        for (int j = 0; j < 4; ++j)
            acc[i][j] = (f32x4){0.f, 0.f, 0.f, 0.f};

    // load frags for K-tile t (BK=32): A chunk cq = (t&7)*4+fq of khw = t>>3;
    // aoff = (t&7)*4*802816 + kh*448 + kw*8  (802816 elems per cq-step)
    auto loadF = [&](int t, Frags& f) {
        const int khw = t >> 3;
        const int kh = (khw * 11) >> 5;          // khw/3 for 0..8
        const int kw = khw - kh * 3;
        const int aoff = (t & 7) * 3211264 + kh * 448 + kw * 8;
        const int boff = t * 8192;
#pragma unroll
        for (int mi = 0; mi < 4; ++mi)
            f.a[mi] = *(const bf16x8*)(a_ptr[mi] + aoff);
#pragma unroll
        for (int ni = 0; ni < 4; ++ni)
            f.b[ni] = *(const bf16x8*)(b_ptr + boff + ni * 128);
    };

    Frags F0, F1;
    loadF(0, F0);

#pragma unroll 1
    for (int t = 0; t < 72; t += 2) {
        loadF(t + 1, F1);
        mfma16(F0, acc);
        if (t + 2 < 72) loadF(t + 2, F0);
        mfma16(F1, acc);
    }

    // ---- epilogue: D col = lane&15 (co), row = (lane>>4)*4 + reg (m); fuse bias ----
    float bv[4];
#pragma unroll
    for (int ni = 0; ni < 4; ++ni) bv[ni] = bias[co0 + wn + ni * 16 + fm];
#pragma unroll
    for (int mi = 0; mi < 4; ++mi) {
#pragma unroll
        for (int reg = 0; reg < 4; ++reg) {
            int m = m0 + wm + mi * 16 + fq * 4 + reg;
            float* orow = Out + m * 256 + co0 + wn + fm;
#pragma unroll
            for (int ni = 0; ni < 4; ++ni)
                orow[ni * 16] = acc[mi][ni][reg] + bv[ni];
        }
    }
}

extern "C" void kernel_launch(void* const* d_in, const int* in_sizes, int n_in,
                              void* d_out, int out_size, void* d_ws, size_t ws_size,
                              hipStream_t stream) {
    const float* x    = (const float*)d_in[0];  // (32,56,56,256) fp32
    const float* w    = (const float*)d_in[1];  // (256,256,3,3) fp32
    const float* bias = (const float*)d_in[2];  // (256,) fp32
    float* out = (float*)d_out;                 // (32,54,54,256) fp32

    const int NX = 32 * 56 * 56 * 256;  // 25,690,112
    unsigned short* xb = (unsigned short*)d_ws;
    unsigned short* wt = xb + NX;

    cvt_xw<<<14592, 256, 0, stream>>>(x, xb, w, wt);
    conv_gemm<<<1458, 256, 0, stream>>>(xb, wt, bias, out);
}